// Round 16
// baseline (659.566 us; speedup 1.0000x reference)
//
#include <hip/hip_runtime.h>

#define NN 512
#define CZv 128
#define CFv 384
#define CPv 256
#define ROWS 64   // pair-rows per block (8 waves x 32-col slice)

typedef __attribute__((ext_vector_type(8))) short s16x8;
typedef __attribute__((ext_vector_type(4))) short s16x4;
typedef __attribute__((ext_vector_type(4))) float f32x4;

__device__ __forceinline__ unsigned short f2bf(float f) {
  unsigned int u = __builtin_bit_cast(unsigned int, f);
  u = (u + 0x7FFFu + ((u >> 16) & 1u)) >> 16;
  return (unsigned short)u;
}
// 2 f32 -> packed 2x bf16 (RNE, identical to f2bf) in ONE VALU op.
__device__ __forceinline__ unsigned int cvt_pk(float lo, float hi) {
  unsigned int r;
  asm("v_cvt_pk_bf16_f32 %0, %1, %2" : "=v"(r) : "v"(lo), "v"(hi));
  return r;
}
__device__ __forceinline__ s16x4 pack4(float a, float b, float c, float d) {
  unsigned int u0 = cvt_pk(a, b), u1 = cvt_pk(c, d);
  unsigned long long v = ((unsigned long long)u1 << 32) | u0;
  return __builtin_bit_cast(s16x4, v);
}

// ---- merged prep: blocks 0..895 pack weights; blocks 896..959 compute l,m ----
__global__ __launch_bounds__(256) void prep_kernel(
    const float* __restrict__ Wz, const float* __restrict__ W1,
    const float* __restrict__ W2, const float* __restrict__ W3,
    short* __restrict__ Wzf, short* __restrict__ W1f,
    short* __restrict__ W2f, short* __restrict__ W3f,
    const float* __restrict__ rf, const float* __restrict__ g, const float* __restrict__ b,
    const float* __restrict__ Wl, const float* __restrict__ Wm,
    float* __restrict__ lout, float* __restrict__ mout) {
  __shared__ float S[8][CFv];
  if (blockIdx.x < 896) {
    int o = blockIdx.x * 256 + threadIdx.x;
    const float* W;
    short* Wf;
    int lo;
    if (o < 32768) { W = Wz; Wf = Wzf; lo = o; }
    else if (o < 98304) { W = W1; Wf = W1f; lo = o - 32768; }
    else if (o < 163840) { W = W2; Wf = W2f; lo = o - 98304; }
    else { W = W3; Wf = W3f; lo = o - 163840; }
    int e = lo & 7;
    int l = (lo >> 3) & 63;
    int mt = (lo >> 9) & 15;
    int kk = lo >> 13;
    int k = kk * 32 + (l >> 4) * 8 + e;
    int p = mt * 16 + (l & 15);
    Wf[lo] = (short)f2bf(W[k * 256 + p]);
    return;
  }
  const int bb = blockIdx.x - 896;
  const int tid = threadIdx.x;
  const int w = tid >> 6;
  const int lane = tid & 63;
  for (int rr = 0; rr < 2; ++rr) {
    int r = bb * 8 + w * 2 + rr;
    const float* x = rf + (long)r * CFv;
    float v[6];
    float s1 = 0.f, s2 = 0.f;
#pragma unroll
    for (int q = 0; q < 6; ++q) {
      v[q] = x[lane + q * 64];
      s1 += v[q];
      s2 += v[q] * v[q];
    }
#pragma unroll
    for (int off = 1; off < 64; off <<= 1) {
      s1 += __shfl_xor(s1, off, 64);
      s2 += __shfl_xor(s2, off, 64);
    }
    float mu = s1 * (1.f / CFv);
    float va = s2 * (1.f / CFv) - mu * mu;
    float rs = rsqrtf(va + 1e-5f);
#pragma unroll
    for (int q = 0; q < 6; ++q) {
      int k = lane + q * 64;
      S[w * 2 + rr][k] = (v[q] - mu) * rs * g[k] + b[k];
    }
  }
  __syncthreads();
  float accl[8], accm[8];
#pragma unroll
  for (int r = 0; r < 8; ++r) { accl[r] = 0.f; accm[r] = 0.f; }
  for (int k = 0; k < CFv; ++k) {
    float wl = Wl[k * CPv + tid];
    float wm = Wm[k * CPv + tid];
#pragma unroll
    for (int r = 0; r < 8; ++r) {
      accl[r] += S[r][k] * wl;
      accm[r] += S[r][k] * wm;
    }
  }
#pragma unroll
  for (int r = 0; r < 8; ++r) {
    long rg = bb * 8 + r;
    lout[rg * CPv + tid] = accl[r];
    mout[rg * CPv + tid] = accm[r];
  }
}

// ---- main fused kernel: 8 waves, 64x256 per block, 36.9 KB LDS, (512,6) ----
// Occupancy push: 3 blocks/CU (24 waves). Xres deleted; fe retires through
// out[] (store fe+b3 at h-write; GEMM4 seeds by reading it back). Reg cap 80:
// acc peak 32 (fe dies before hacc born), arch ~74 peak in FFN region.
// Spill canary: WRITE >> 600 MB (expected ~524 MB = 2x output).
__global__ __launch_bounds__(512, 6) void fused_main(
    const float* __restrict__ z, const float* __restrict__ fpe,
    const int* __restrict__ idx, const float* __restrict__ msk,
    const float* __restrict__ lnzg, const float* __restrict__ lnzb,
    const float* __restrict__ ffng, const float* __restrict__ ffnb,
    const float* __restrict__ b1p, const float* __restrict__ b2p, const float* __restrict__ b3p,
    const float* __restrict__ lws, const float* __restrict__ mws,
    const short* __restrict__ Wzf, const short* __restrict__ W1f,
    const short* __restrict__ W2f, const short* __restrict__ W3f,
    float* __restrict__ out) {
  // X (32 KB): zb bf16 [64][128] (lower 16 KB) until GEMM1; then h/h1/h2
  //            bf16 [64][256] (stride 512B, swizzled), rewritten in place.
  __shared__ __align__(16) char X[ROWS * CPv * 2];
  __shared__ float SS[8][ROWS];
  __shared__ float SQ[8][ROWS];

  const int tid = threadIdx.x;
  const int w = tid >> 6;       // 0..7
  const int lane = tid & 63;
  const int l15 = lane & 15;
  const int lg = lane >> 4;
  const int mt0 = 2 * w;

  const int b = blockIdx.x;
  const int tile = (b & 7) * 512 + (b >> 3);
  const int i = tile >> 3;
  const int j0 = (tile & 7) * ROWS;
  const int r0 = tile * ROWS;

  // ---------- Phase Z first (keeps z-phase reg peak low) ----------
  {
    const int row = w * 8 + (lane & 7);
    const int seg = (lane >> 3) * 16;
    const int j = j0 + row;
    const int ia = idx[i];
    const int jb = idx[j];
    const float pm = msk[i] * msk[j];
    const float* zr = z + ((long)ia * NN + jb) * CZv + seg;
    f32x4 zv[4];
    float s1 = 0.f, s2 = 0.f;
#pragma unroll
    for (int q = 0; q < 4; ++q) {
      zv[q] = *(const f32x4*)(zr + q * 4);
#pragma unroll
      for (int e = 0; e < 4; ++e) {
        float v = zv[q][e] * pm;
        zv[q][e] = v;
        s1 += v;
        s2 += v * v;
      }
    }
    s1 += __shfl_xor(s1, 8, 64);
    s1 += __shfl_xor(s1, 16, 64);
    s1 += __shfl_xor(s1, 32, 64);
    s2 += __shfl_xor(s2, 8, 64);
    s2 += __shfl_xor(s2, 16, 64);
    s2 += __shfl_xor(s2, 32, 64);
    float mu = s1 * (1.f / CZv);
    float va = s2 * (1.f / CZv) - mu * mu;
    float rs = rsqrtf(va + 1e-5f);
    const int swz = (row & 7) << 4;
#pragma unroll
    for (int h = 0; h < 2; ++h) {
      const f32x4 g0 = *(const f32x4*)(lnzg + seg + h * 8);
      const f32x4 g1 = *(const f32x4*)(lnzg + seg + h * 8 + 4);
      const f32x4 q0 = *(const f32x4*)(lnzb + seg + h * 8);
      const f32x4 q1 = *(const f32x4*)(lnzb + seg + h * 8 + 4);
      float t[8];
#pragma unroll
      for (int e = 0; e < 4; ++e) {
        t[e] = (zv[h * 2][e] - mu) * rs * g0[e] + q0[e];
        t[4 + e] = (zv[h * 2 + 1][e] - mu) * rs * g1[e] + q1[e];
      }
      unsigned int u0 = cvt_pk(t[0], t[1]), u1 = cvt_pk(t[2], t[3]);
      unsigned int u2 = cvt_pk(t[4], t[5]), u3 = cvt_pk(t[6], t[7]);
      s16x8 hv;
      {
        unsigned int uu[4] = {u0, u1, u2, u3};
        hv = __builtin_bit_cast(s16x8, *(ulong2*)uu);
      }
      int off = (row * 256 + seg * 2 + h * 16) ^ swz;
      *(s16x8*)(X + off) = hv;
    }
  }

  // ---------- acc init: fe = framepair + l_i + m_j ----------
  f32x4 fe[4][2];
  {
    f32x4 lb[2];
    const float* lr = lws + (long)i * CPv;
#pragma unroll
    for (int mi = 0; mi < 2; ++mi)
      lb[mi] = *(const f32x4*)(lr + (mt0 + mi) * 16 + lg * 4);
#pragma unroll
    for (int nt = 0; nt < 4; ++nt) {
      const int row = nt * 16 + l15;
      const long rg = (long)r0 + row;
      const float* fpr = fpe + rg * CPv;
      const float* mr = mws + (long)(j0 + row) * CPv;
#pragma unroll
      for (int mi = 0; mi < 2; ++mi) {
        const int c0 = (mt0 + mi) * 16 + lg * 4;
        f32x4 a = *(const f32x4*)(fpr + c0);
        f32x4 mb = *(const f32x4*)(mr + c0);
        fe[nt][mi] = a + lb[mi] + mb;
      }
    }
  }
  __syncthreads();  // B1: zb visible

  // ---------- GEMM1: fe += LN(zb) @ W_z  (K=128), 1-deep weight prefetch ----------
  {
    const s16x8* Wp = (const s16x8*)Wzf;
    s16x8 af[2][2];
#pragma unroll
    for (int mi = 0; mi < 2; ++mi) af[0][mi] = Wp[(mt0 + mi) * 64 + lane];
    __builtin_amdgcn_s_setprio(1);
#pragma unroll
    for (int kk = 0; kk < 4; ++kk) {
      const int cur = kk & 1;
      if (kk < 3) {
#pragma unroll
        for (int mi = 0; mi < 2; ++mi)
          af[cur ^ 1][mi] = Wp[((kk + 1) * 16 + mt0 + mi) * 64 + lane];
      }
#pragma unroll
      for (int nt = 0; nt < 4; ++nt) {
        const int row = nt * 16 + l15;
        int off = (row * 256 + kk * 64 + lg * 16) ^ ((row & 7) << 4);
        s16x8 bfr = *(const s16x8*)(X + off);
#pragma unroll
        for (int mi = 0; mi < 2; ++mi)
          fe[nt][mi] = __builtin_amdgcn_mfma_f32_16x16x32_bf16(af[cur][mi], bfr, fe[nt][mi], 0, 0, 0);
      }
    }
    __builtin_amdgcn_s_setprio(0);
  }

  // ---------- LN(fe) stats (8-wave cross reduce) ----------
  float mu4[4], rs4[4];
  {
#pragma unroll
    for (int nt = 0; nt < 4; ++nt) {
      float s = 0.f, q = 0.f;
#pragma unroll
      for (int mi = 0; mi < 2; ++mi)
#pragma unroll
        for (int e = 0; e < 4; ++e) {
          float v = fe[nt][mi][e];
          s += v;
          q += v * v;
        }
      s += __shfl_xor(s, 16, 64);
      s += __shfl_xor(s, 32, 64);
      q += __shfl_xor(q, 16, 64);
      q += __shfl_xor(q, 32, 64);
      if (lane < 16) {
        SS[w][nt * 16 + lane] = s;
        SQ[w][nt * 16 + lane] = q;
      }
    }
    __syncthreads();  // B2: stats visible; all GEMM1 X-reads done
#pragma unroll
    for (int nt = 0; nt < 4; ++nt) {
      const int row = nt * 16 + l15;
      float ts = 0.f, tq = 0.f;
#pragma unroll
      for (int ww = 0; ww < 8; ++ww) {
        ts += SS[ww][row];
        tq += SQ[ww][row];
      }
      float mu = ts * (1.f / CPv);
      float va = tq * (1.f / CPv) - mu * mu;
      mu4[nt] = mu;
      rs4[nt] = rsqrtf(va + 1e-5f);
    }
  }

  // ---------- h = LN(fe)*g+b -> X; retire fe: out = fe + b3 ----------
#pragma unroll
  for (int mi = 0; mi < 2; ++mi) {
    const int c0 = (mt0 + mi) * 16 + lg * 4;
    const f32x4 g4 = *(const f32x4*)(ffng + c0);
    const f32x4 b4 = *(const f32x4*)(ffnb + c0);
    const f32x4 b34 = *(const f32x4*)(b3p + c0);
#pragma unroll
    for (int nt = 0; nt < 4; ++nt) {
      const int row = nt * 16 + l15;
      const int swz = (row & 7) << 4;
      float h0 = (fe[nt][mi][0] - mu4[nt]) * rs4[nt] * g4[0] + b4[0];
      float h1 = (fe[nt][mi][1] - mu4[nt]) * rs4[nt] * g4[1] + b4[1];
      float h2 = (fe[nt][mi][2] - mu4[nt]) * rs4[nt] * g4[2] + b4[2];
      float h3 = (fe[nt][mi][3] - mu4[nt]) * rs4[nt] * g4[3] + b4[3];
      s16x4 hv = pack4(h0, h1, h2, h3);
      int off = (row * 512 + c0 * 2) ^ swz;
      *(s16x4*)(X + off) = hv;
      const long rg = (long)r0 + row;
      *(f32x4*)(out + rg * CPv + c0) = fe[nt][mi] + b34;
    }
  }
  __syncthreads();  // B3: h visible

  // ---------- FFN GEMM (reads X), 1-deep weight prefetch ----------
  auto ffn_gemm = [&](const short* Wf, f32x4(&acc)[4][2]) {
    const s16x8* Wp = (const s16x8*)Wf;
    s16x8 af[2][2];
#pragma unroll
    for (int mi = 0; mi < 2; ++mi) af[0][mi] = Wp[(mt0 + mi) * 64 + lane];
    __builtin_amdgcn_s_setprio(1);
#pragma unroll
    for (int kk = 0; kk < 8; ++kk) {
      const int cur = kk & 1;
      if (kk < 7) {
#pragma unroll
        for (int mi = 0; mi < 2; ++mi)
          af[cur ^ 1][mi] = Wp[((kk + 1) * 16 + mt0 + mi) * 64 + lane];
      }
#pragma unroll
      for (int nt = 0; nt < 4; ++nt) {
        const int row = nt * 16 + l15;
        int off = (row * 512 + kk * 64 + lg * 16) ^ ((row & 7) << 4);
        s16x8 bfr = *(const s16x8*)(X + off);
#pragma unroll
        for (int mi = 0; mi < 2; ++mi)
          acc[nt][mi] = __builtin_amdgcn_mfma_f32_16x16x32_bf16(af[cur][mi], bfr, acc[nt][mi], 0, 0, 0);
      }
    }
    __builtin_amdgcn_s_setprio(0);
  };

  auto write_relu = [&](f32x4(&acc)[4][2]) {
#pragma unroll
    for (int nt = 0; nt < 4; ++nt) {
      const int row = nt * 16 + l15;
      const int swz = (row & 7) << 4;
#pragma unroll
      for (int mi = 0; mi < 2; ++mi) {
        const int c0 = (mt0 + mi) * 16 + lg * 4;
        float v0 = fmaxf(acc[nt][mi][0], 0.f);
        float v1 = fmaxf(acc[nt][mi][1], 0.f);
        float v2 = fmaxf(acc[nt][mi][2], 0.f);
        float v3 = fmaxf(acc[nt][mi][3], 0.f);
        s16x4 hv = pack4(v0, v1, v2, v3);
        int off = (row * 512 + c0 * 2) ^ swz;
        *(s16x4*)(X + off) = hv;
      }
    }
  };

  // ---------- GEMM2: h1 = relu(h@W1 + b1) ----------
  f32x4 hacc[4][2];
#pragma unroll
  for (int mi = 0; mi < 2; ++mi) {
    const f32x4 bini = *(const f32x4*)(b1p + (mt0 + mi) * 16 + lg * 4);
#pragma unroll
    for (int nt = 0; nt < 4; ++nt) hacc[nt][mi] = bini;
  }
  ffn_gemm(W1f, hacc);
  __syncthreads();  // B4: all GEMM2 X-reads done
  write_relu(hacc);
  __syncthreads();  // B5: h1 visible

  // ---------- GEMM3: h2 = relu(h1@W2 + b2) ----------
#pragma unroll
  for (int mi = 0; mi < 2; ++mi) {
    const f32x4 bini = *(const f32x4*)(b2p + (mt0 + mi) * 16 + lg * 4);
#pragma unroll
    for (int nt = 0; nt < 4; ++nt) hacc[nt][mi] = bini;
  }
  ffn_gemm(W2f, hacc);
  __syncthreads();  // B6: all GEMM3 X-reads done
  write_relu(hacc);
  __syncthreads();  // B7: h2 visible

  // ---------- GEMM4: hacc = out-readback (fe+b3); hacc += h2@W3; store ----------
#pragma unroll
  for (int nt = 0; nt < 4; ++nt) {
    const long rg = (long)r0 + nt * 16 + l15;
#pragma unroll
    for (int mi = 0; mi < 2; ++mi) {
      const int c0 = (mt0 + mi) * 16 + lg * 4;
      hacc[nt][mi] = *(const f32x4*)(out + rg * CPv + c0);
    }
  }
  ffn_gemm(W3f, hacc);
#pragma unroll
  for (int nt = 0; nt < 4; ++nt) {
    const long rg = (long)r0 + nt * 16 + l15;
#pragma unroll
    for (int mi = 0; mi < 2; ++mi) {
      const int c0 = (mt0 + mi) * 16 + lg * 4;
      *(f32x4*)(out + rg * CPv + c0) = hacc[nt][mi];
    }
  }
}

extern "C" void kernel_launch(void* const* d_in, const int* in_sizes, int n_in,
                              void* d_out, int out_size, void* d_ws, size_t ws_size,
                              hipStream_t stream) {
  const float* z = (const float*)d_in[0];
  const float* fpe = (const float*)d_in[1];
  const float* rf = (const float*)d_in[2];
  const int* idx = (const int*)d_in[3];
  const float* msk = (const float*)d_in[4];
  const float* lnzg = (const float*)d_in[5];
  const float* lnzb = (const float*)d_in[6];
  const float* Wz = (const float*)d_in[7];
  const float* lnfg = (const float*)d_in[8];
  const float* lnfb = (const float*)d_in[9];
  const float* Wl = (const float*)d_in[10];
  const float* Wm = (const float*)d_in[11];
  const float* ffng = (const float*)d_in[12];
  const float* ffnb = (const float*)d_in[13];
  const float* W1 = (const float*)d_in[14];
  const float* b1 = (const float*)d_in[15];
  const float* W2 = (const float*)d_in[16];
  const float* b2 = (const float*)d_in[17];
  const float* W3 = (const float*)d_in[18];
  const float* b3 = (const float*)d_in[19];
  float* out = (float*)d_out;

  char* ws = (char*)d_ws;
  float* lws = (float*)ws;                               // 512 KB
  float* mws = (float*)(ws + 512 * 1024);                // 512 KB
  short* Wzf = (short*)(ws + 1024 * 1024);               // 64 KB
  short* W1f = (short*)(ws + 1024 * 1024 + 64 * 1024);   // 128 KB
  short* W2f = (short*)(ws + 1024 * 1024 + 192 * 1024);  // 128 KB
  short* W3f = (short*)(ws + 1024 * 1024 + 320 * 1024);  // 128 KB

  prep_kernel<<<960, 256, 0, stream>>>(Wz, W1, W2, W3, Wzf, W1f, W2f, W3f,
                                       rf, lnfg, lnfb, Wl, Wm, lws, mws);
  fused_main<<<4096, 512, 0, stream>>>(z, fpe, idx, msk, lnzg, lnzb, ffng, ffnb,
                                       b1, b2, b3, lws, mws, Wzf, W1f, W2f, W3f, out);
}

// Round 17
// 298.315 us; speedup vs baseline: 2.2110x; 2.2110x over previous
//
#include <hip/hip_runtime.h>

#define NN 512
#define CZv 128
#define CFv 384
#define CPv 256
#define ROWS 64   // pair-rows per block (8 waves x 32-col slice)

typedef __attribute__((ext_vector_type(8))) short s16x8;
typedef __attribute__((ext_vector_type(4))) short s16x4;
typedef __attribute__((ext_vector_type(4))) float f32x4;

__device__ __forceinline__ unsigned short f2bf(float f) {
  unsigned int u = __builtin_bit_cast(unsigned int, f);
  u = (u + 0x7FFFu + ((u >> 16) & 1u)) >> 16;
  return (unsigned short)u;
}
__device__ __forceinline__ float bf2f(unsigned short h) {
  unsigned int u = ((unsigned int)h) << 16;
  return __builtin_bit_cast(float, u);
}
// 2 f32 -> packed 2x bf16 (RNE, identical to f2bf) in ONE VALU op.
__device__ __forceinline__ unsigned int cvt_pk(float lo, float hi) {
  unsigned int r;
  asm("v_cvt_pk_bf16_f32 %0, %1, %2" : "=v"(r) : "v"(lo), "v"(hi));
  return r;
}
__device__ __forceinline__ s16x4 pack4(float a, float b, float c, float d) {
  unsigned int u0 = cvt_pk(a, b), u1 = cvt_pk(c, d);
  unsigned long long v = ((unsigned long long)u1 << 32) | u0;
  return __builtin_bit_cast(s16x4, v);
}

// ---- merged prep: blocks 0..895 pack weights; blocks 896..959 compute l,m ----
__global__ __launch_bounds__(256) void prep_kernel(
    const float* __restrict__ Wz, const float* __restrict__ W1,
    const float* __restrict__ W2, const float* __restrict__ W3,
    short* __restrict__ Wzf, short* __restrict__ W1f,
    short* __restrict__ W2f, short* __restrict__ W3f,
    const float* __restrict__ rf, const float* __restrict__ g, const float* __restrict__ b,
    const float* __restrict__ Wl, const float* __restrict__ Wm,
    float* __restrict__ lout, float* __restrict__ mout) {
  __shared__ float S[8][CFv];
  if (blockIdx.x < 896) {
    int o = blockIdx.x * 256 + threadIdx.x;
    const float* W;
    short* Wf;
    int lo;
    if (o < 32768) { W = Wz; Wf = Wzf; lo = o; }
    else if (o < 98304) { W = W1; Wf = W1f; lo = o - 32768; }
    else if (o < 163840) { W = W2; Wf = W2f; lo = o - 98304; }
    else { W = W3; Wf = W3f; lo = o - 163840; }
    int e = lo & 7;
    int l = (lo >> 3) & 63;
    int mt = (lo >> 9) & 15;
    int kk = lo >> 13;
    int k = kk * 32 + (l >> 4) * 8 + e;
    int p = mt * 16 + (l & 15);
    Wf[lo] = (short)f2bf(W[k * 256 + p]);
    return;
  }
  const int bb = blockIdx.x - 896;
  const int tid = threadIdx.x;
  const int w = tid >> 6;
  const int lane = tid & 63;
  for (int rr = 0; rr < 2; ++rr) {
    int r = bb * 8 + w * 2 + rr;
    const float* x = rf + (long)r * CFv;
    float v[6];
    float s1 = 0.f, s2 = 0.f;
#pragma unroll
    for (int q = 0; q < 6; ++q) {
      v[q] = x[lane + q * 64];
      s1 += v[q];
      s2 += v[q] * v[q];
    }
#pragma unroll
    for (int off = 1; off < 64; off <<= 1) {
      s1 += __shfl_xor(s1, off, 64);
      s2 += __shfl_xor(s2, off, 64);
    }
    float mu = s1 * (1.f / CFv);
    float va = s2 * (1.f / CFv) - mu * mu;
    float rs = rsqrtf(va + 1e-5f);
#pragma unroll
    for (int q = 0; q < 6; ++q) {
      int k = lane + q * 64;
      S[w * 2 + rr][k] = (v[q] - mu) * rs * g[k] + b[k];
    }
  }
  __syncthreads();
  float accl[8], accm[8];
#pragma unroll
  for (int r = 0; r < 8; ++r) { accl[r] = 0.f; accm[r] = 0.f; }
  for (int k = 0; k < CFv; ++k) {
    float wl = Wl[k * CPv + tid];
    float wm = Wm[k * CPv + tid];
#pragma unroll
    for (int r = 0; r < 8; ++r) {
      accl[r] += S[r][k] * wl;
      accm[r] += S[r][k] * wm;
    }
  }
#pragma unroll
  for (int r = 0; r < 8; ++r) {
    long rg = bb * 8 + r;
    lout[rg * CPv + tid] = accl[r];
    mout[rg * CPv + tid] = accm[r];
  }
}

// ---- main fused kernel: EXACT R13/R15 structure (best verified: 287 us) ----
// fe residual lives in Xres (LDS, same-thread write/read); acc = 32 in FFN
// phases; arch ~55+prefetch. The only spill-free 64-row config; >2 blocks/CU
// spills in all 8 variants tried (R2/R3/R4/R7/R8/R10/R14/R16).
__global__ __launch_bounds__(512, 4) void fused_main(
    const float* __restrict__ z, const float* __restrict__ fpe,
    const int* __restrict__ idx, const float* __restrict__ msk,
    const float* __restrict__ lnzg, const float* __restrict__ lnzb,
    const float* __restrict__ ffng, const float* __restrict__ ffnb,
    const float* __restrict__ b1p, const float* __restrict__ b2p, const float* __restrict__ b3p,
    const float* __restrict__ lws, const float* __restrict__ mws,
    const short* __restrict__ Wzf, const short* __restrict__ W1f,
    const short* __restrict__ W2f, const short* __restrict__ W3f,
    float* __restrict__ out) {
  __shared__ __align__(16) char X[ROWS * CPv * 2];
  __shared__ __align__(16) char Xres[ROWS * CPv * 2];
  __shared__ float SS[8][ROWS];
  __shared__ float SQ[8][ROWS];

  const int tid = threadIdx.x;
  const int w = tid >> 6;       // 0..7
  const int lane = tid & 63;
  const int l15 = lane & 15;
  const int lg = lane >> 4;
  const int mt0 = 2 * w;

  const int b = blockIdx.x;
  const int tile = (b & 7) * 512 + (b >> 3);
  const int i = tile >> 3;
  const int j0 = (tile & 7) * ROWS;
  const int r0 = tile * ROWS;

  // ---------- acc init: fe = framepair + l_i + m_j ----------
  f32x4 fe[4][2];
  {
    f32x4 lb[2];
    const float* lr = lws + (long)i * CPv;
#pragma unroll
    for (int mi = 0; mi < 2; ++mi)
      lb[mi] = *(const f32x4*)(lr + (mt0 + mi) * 16 + lg * 4);
#pragma unroll
    for (int nt = 0; nt < 4; ++nt) {
      const int row = nt * 16 + l15;
      const long rg = (long)r0 + row;
      const float* fpr = fpe + rg * CPv;
      const float* mr = mws + (long)(j0 + row) * CPv;
#pragma unroll
      for (int mi = 0; mi < 2; ++mi) {
        const int c0 = (mt0 + mi) * 16 + lg * 4;
        f32x4 a = *(const f32x4*)(fpr + c0);
        f32x4 mb = *(const f32x4*)(mr + c0);
        fe[nt][mi] = a + lb[mi] + mb;
      }
    }
  }

  // ---------- Phase Z: wave w gathers+LNs rows 8w..8w+7 of zb ----------
  {
    const int row = w * 8 + (lane & 7);
    const int seg = (lane >> 3) * 16;
    const int j = j0 + row;
    const int ia = idx[i];
    const int jb = idx[j];
    const float pm = msk[i] * msk[j];
    const float* zr = z + ((long)ia * NN + jb) * CZv + seg;
    f32x4 zv[4];
    float s1 = 0.f, s2 = 0.f;
#pragma unroll
    for (int q = 0; q < 4; ++q) {
      zv[q] = *(const f32x4*)(zr + q * 4);
#pragma unroll
      for (int e = 0; e < 4; ++e) {
        float v = zv[q][e] * pm;
        zv[q][e] = v;
        s1 += v;
        s2 += v * v;
      }
    }
    s1 += __shfl_xor(s1, 8, 64);
    s1 += __shfl_xor(s1, 16, 64);
    s1 += __shfl_xor(s1, 32, 64);
    s2 += __shfl_xor(s2, 8, 64);
    s2 += __shfl_xor(s2, 16, 64);
    s2 += __shfl_xor(s2, 32, 64);
    float mu = s1 * (1.f / CZv);
    float va = s2 * (1.f / CZv) - mu * mu;
    float rs = rsqrtf(va + 1e-5f);
    const int swz = (row & 7) << 4;
#pragma unroll
    for (int h = 0; h < 2; ++h) {
      const f32x4 g0 = *(const f32x4*)(lnzg + seg + h * 8);
      const f32x4 g1 = *(const f32x4*)(lnzg + seg + h * 8 + 4);
      const f32x4 q0 = *(const f32x4*)(lnzb + seg + h * 8);
      const f32x4 q1 = *(const f32x4*)(lnzb + seg + h * 8 + 4);
      float t[8];
#pragma unroll
      for (int e = 0; e < 4; ++e) {
        t[e] = (zv[h * 2][e] - mu) * rs * g0[e] + q0[e];
        t[4 + e] = (zv[h * 2 + 1][e] - mu) * rs * g1[e] + q1[e];
      }
      unsigned int u0 = cvt_pk(t[0], t[1]), u1 = cvt_pk(t[2], t[3]);
      unsigned int u2 = cvt_pk(t[4], t[5]), u3 = cvt_pk(t[6], t[7]);
      s16x8 hv;
      {
        unsigned int uu[4] = {u0, u1, u2, u3};
        hv = __builtin_bit_cast(s16x8, *(ulong2*)uu);
      }
      int off = (row * 256 + seg * 2 + h * 16) ^ swz;
      *(s16x8*)(X + off) = hv;
    }
  }
  __syncthreads();  // B1

  // ---------- GEMM1: fe += LN(zb) @ W_z  (K=128), 2-deep weight prefetch ----------
  {
    const s16x8* Wp = (const s16x8*)Wzf;
    auto ldw = [&](int kk, s16x8(&a)[2]) {
      a[0] = Wp[(kk * 16 + mt0 + 0) * 64 + lane];
      a[1] = Wp[(kk * 16 + mt0 + 1) * 64 + lane];
    };
    auto step = [&](int kk, const s16x8(&a)[2]) {
#pragma unroll
      for (int nt = 0; nt < 4; ++nt) {
        const int row = nt * 16 + l15;
        int off = (row * 256 + kk * 64 + lg * 16) ^ ((row & 7) << 4);
        s16x8 bfr = *(const s16x8*)(X + off);
#pragma unroll
        for (int mi = 0; mi < 2; ++mi)
          fe[nt][mi] = __builtin_amdgcn_mfma_f32_16x16x32_bf16(a[mi], bfr, fe[nt][mi], 0, 0, 0);
      }
    };
    s16x8 afA[2], afB[2], afC[2];
    ldw(0, afA);
    ldw(1, afB);
    __builtin_amdgcn_s_setprio(1);
    ldw(2, afC);
    step(0, afA);
    ldw(3, afA);
    step(1, afB);
    step(2, afC);
    step(3, afA);
    __builtin_amdgcn_s_setprio(0);
  }

  // ---------- LN(fe) stats (8-wave cross reduce) ----------
  float mu4[4], rs4[4];
  {
#pragma unroll
    for (int nt = 0; nt < 4; ++nt) {
      float s = 0.f, q = 0.f;
#pragma unroll
      for (int mi = 0; mi < 2; ++mi)
#pragma unroll
        for (int e = 0; e < 4; ++e) {
          float v = fe[nt][mi][e];
          s += v;
          q += v * v;
        }
      s += __shfl_xor(s, 16, 64);
      s += __shfl_xor(s, 32, 64);
      q += __shfl_xor(q, 16, 64);
      q += __shfl_xor(q, 32, 64);
      if (lane < 16) {
        SS[w][nt * 16 + lane] = s;
        SQ[w][nt * 16 + lane] = q;
      }
    }
    __syncthreads();  // B2: stats visible; all GEMM1 X-reads done
#pragma unroll
    for (int nt = 0; nt < 4; ++nt) {
      const int row = nt * 16 + l15;
      float ts = 0.f, tq = 0.f;
#pragma unroll
      for (int ww = 0; ww < 8; ++ww) {
        ts += SS[ww][row];
        tq += SQ[ww][row];
      }
      float mu = ts * (1.f / CPv);
      float va = tq * (1.f / CPv) - mu * mu;
      mu4[nt] = mu;
      rs4[nt] = rsqrtf(va + 1e-5f);
    }
  }

  // ---------- h = LN(fe)*g+b -> X; fe residual bf16 -> Xres ----------
#pragma unroll
  for (int mi = 0; mi < 2; ++mi) {
    const int c0 = (mt0 + mi) * 16 + lg * 4;
    const f32x4 g4 = *(const f32x4*)(ffng + c0);
    const f32x4 b4 = *(const f32x4*)(ffnb + c0);
#pragma unroll
    for (int nt = 0; nt < 4; ++nt) {
      const int row = nt * 16 + l15;
      const int swz = (row & 7) << 4;
      float h0 = (fe[nt][mi][0] - mu4[nt]) * rs4[nt] * g4[0] + b4[0];
      float h1 = (fe[nt][mi][1] - mu4[nt]) * rs4[nt] * g4[1] + b4[1];
      float h2 = (fe[nt][mi][2] - mu4[nt]) * rs4[nt] * g4[2] + b4[2];
      float h3 = (fe[nt][mi][3] - mu4[nt]) * rs4[nt] * g4[3] + b4[3];
      s16x4 hv = pack4(h0, h1, h2, h3);
      s16x4 fv = pack4(fe[nt][mi][0], fe[nt][mi][1], fe[nt][mi][2], fe[nt][mi][3]);
      int off = (row * 512 + c0 * 2) ^ swz;
      *(s16x4*)(X + off) = hv;
      *(s16x4*)(Xres + off) = fv;
    }
  }
  __syncthreads();  // B3

  // ---------- FFN GEMM (reads X), 2-deep weight prefetch (3-buffer rotation) ----------
  auto ffn_gemm = [&](const short* Wf, f32x4(&acc)[4][2]) {
    const s16x8* Wp = (const s16x8*)Wf;
    auto ldw = [&](int kk, s16x8(&a)[2]) {
      a[0] = Wp[(kk * 16 + mt0 + 0) * 64 + lane];
      a[1] = Wp[(kk * 16 + mt0 + 1) * 64 + lane];
    };
    auto step = [&](int kk, const s16x8(&a)[2]) {
#pragma unroll
      for (int nt = 0; nt < 4; ++nt) {
        const int row = nt * 16 + l15;
        int off = (row * 512 + kk * 64 + lg * 16) ^ ((row & 7) << 4);
        s16x8 bfr = *(const s16x8*)(X + off);
#pragma unroll
        for (int mi = 0; mi < 2; ++mi)
          acc[nt][mi] = __builtin_amdgcn_mfma_f32_16x16x32_bf16(a[mi], bfr, acc[nt][mi], 0, 0, 0);
      }
    };
    s16x8 afA[2], afB[2], afC[2];
    ldw(0, afA);
    ldw(1, afB);
    __builtin_amdgcn_s_setprio(1);
    ldw(2, afC);
    step(0, afA);
    ldw(3, afA);
    step(1, afB);
    ldw(4, afB);
    step(2, afC);
    ldw(5, afC);
    step(3, afA);
    ldw(6, afA);
    step(4, afB);
    ldw(7, afB);
    step(5, afC);
    step(6, afA);
    step(7, afB);
    __builtin_amdgcn_s_setprio(0);
  };

  auto write_relu = [&](f32x4(&acc)[4][2]) {
#pragma unroll
    for (int nt = 0; nt < 4; ++nt) {
      const int row = nt * 16 + l15;
      const int swz = (row & 7) << 4;
#pragma unroll
      for (int mi = 0; mi < 2; ++mi) {
        const int c0 = (mt0 + mi) * 16 + lg * 4;
        float v0 = fmaxf(acc[nt][mi][0], 0.f);
        float v1 = fmaxf(acc[nt][mi][1], 0.f);
        float v2 = fmaxf(acc[nt][mi][2], 0.f);
        float v3 = fmaxf(acc[nt][mi][3], 0.f);
        s16x4 hv = pack4(v0, v1, v2, v3);
        int off = (row * 512 + c0 * 2) ^ swz;
        *(s16x4*)(X + off) = hv;
      }
    }
  };

  // ---------- GEMM2: h1 = relu(h@W1 + b1) ----------
  f32x4 hacc[4][2];
#pragma unroll
  for (int mi = 0; mi < 2; ++mi) {
    const f32x4 bini = *(const f32x4*)(b1p + (mt0 + mi) * 16 + lg * 4);
#pragma unroll
    for (int nt = 0; nt < 4; ++nt) hacc[nt][mi] = bini;
  }
  ffn_gemm(W1f, hacc);
  __syncthreads();  // B4: all GEMM2 X-reads done
  write_relu(hacc);
  __syncthreads();  // B5: h1 visible

  // ---------- GEMM3: h2 = relu(h1@W2 + b2) ----------
#pragma unroll
  for (int mi = 0; mi < 2; ++mi) {
    const f32x4 bini = *(const f32x4*)(b2p + (mt0 + mi) * 16 + lg * 4);
#pragma unroll
    for (int nt = 0; nt < 4; ++nt) hacc[nt][mi] = bini;
  }
  ffn_gemm(W2f, hacc);
  __syncthreads();  // B6: all GEMM3 X-reads done
  write_relu(hacc);
  __syncthreads();  // B7: h2 visible

  // ---------- GEMM4: out = fe + h2@W3 + b3 (acc re-seeded from Xres) ----------
#pragma unroll
  for (int mi = 0; mi < 2; ++mi) {
    const f32x4 b34 = *(const f32x4*)(b3p + (mt0 + mi) * 16 + lg * 4);
    const int c0 = (mt0 + mi) * 16 + lg * 4;
#pragma unroll
    for (int nt = 0; nt < 4; ++nt) {
      const int row = nt * 16 + l15;
      const int swz = (row & 7) << 4;
      int off = (row * 512 + c0 * 2) ^ swz;
      s16x4 fv = *(const s16x4*)(Xres + off);
#pragma unroll
      for (int e = 0; e < 4; ++e)
        hacc[nt][mi][e] = bf2f((unsigned short)fv[e]) + b34[e];
    }
  }
  ffn_gemm(W3f, hacc);
#pragma unroll
  for (int nt = 0; nt < 4; ++nt) {
    const long rg = (long)r0 + nt * 16 + l15;
#pragma unroll
    for (int mi = 0; mi < 2; ++mi) {
      const int c0 = (mt0 + mi) * 16 + lg * 4;
      *(f32x4*)(out + rg * CPv + c0) = hacc[nt][mi];
    }
  }
}

extern "C" void kernel_launch(void* const* d_in, const int* in_sizes, int n_in,
                              void* d_out, int out_size, void* d_ws, size_t ws_size,
                              hipStream_t stream) {
  const float* z = (const float*)d_in[0];
  const float* fpe = (const float*)d_in[1];
  const float* rf = (const float*)d_in[2];
  const int* idx = (const int*)d_in[3];
  const float* msk = (const float*)d_in[4];
  const float* lnzg = (const float*)d_in[5];
  const float* lnzb = (const float*)d_in[6];
  const float* Wz = (const float*)d_in[7];
  const float* lnfg = (const float*)d_in[8];
  const float* lnfb = (const float*)d_in[9];
  const float* Wl = (const float*)d_in[10];
  const float* Wm = (const float*)d_in[11];
  const float* ffng = (const float*)d_in[12];
  const float* ffnb = (const float*)d_in[13];
  const float* W1 = (const float*)d_in[14];
  const float* b1 = (const float*)d_in[15];
  const float* W2 = (const float*)d_in[16];
  const float* b2 = (const float*)d_in[17];
  const float* W3 = (const float*)d_in[18];
  const float* b3 = (const float*)d_in[19];
  float* out = (float*)d_out;

  char* ws = (char*)d_ws;
  float* lws = (float*)ws;                               // 512 KB
  float* mws = (float*)(ws + 512 * 1024);                // 512 KB
  short* Wzf = (short*)(ws + 1024 * 1024);               // 64 KB
  short* W1f = (short*)(ws + 1024 * 1024 + 64 * 1024);   // 128 KB
  short* W2f = (short*)(ws + 1024 * 1024 + 192 * 1024);  // 128 KB
  short* W3f = (short*)(ws + 1024 * 1024 + 320 * 1024);  // 128 KB

  prep_kernel<<<960, 256, 0, stream>>>(Wz, W1, W2, W3, Wzf, W1f, W2f, W3f,
                                       rf, lnfg, lnfb, Wl, Wm, lws, mws);
  fused_main<<<4096, 512, 0, stream>>>(z, fpe, idx, msk, lnzg, lnzb, ffng, ffnb,
                                       b1, b2, b3, lws, mws, Wzf, W1f, W2f, W3f, out);
}